// Round 10
// baseline (657.368 us; speedup 1.0000x reference)
//
#include <hip/hip_runtime.h>

// Problem dims (from reference setup_inputs): T=256, B=128, I=512, H=512
#define T_STEPS 256
#define B_DIM   128
#define I_DIM   512
#define H_DIM   512
#define M_DIM   (T_STEPS * B_DIM)   // 32768 rows of the flattened GEMM

// ===================== GEMM: scalar-A / LDS-B structure =====================
// h[m][n] = sum_k x[m][k] * W[n][k] + b[n]
//
// WHY: the 8x8-fragment kernel (212 us) is LDS-pipe-bound: per wave per
// k-step it reads A (2 b128) + B (2 b128) = 48 LDS-cyc vs 128 FMA-cyc;
// 4 retiring waves/CU -> 216/128 = 1.69x oversubscribed -> duty ceiling
// ~59% (measured 51%). Enlarging the fragment (8x16) failed 4x (R2/3/5/9):
// LLVM's occupancy heuristic always collapses the 128-reg-acc pipeline
// (spill / load-sinking / ILP-throttling at VGPR=132). CLOSED.
//
// THIS kernel removes A from LDS instead of enlarging the fragment:
//   - wave owns 8 m-rows x ALL 512 n-cols; lane owns n = 8*lane..8*lane+7.
//   - A values are WAVE-UNIFORM -> uniform loads from const-restrict global
//     -> scalar (s_load)/L1 path, zero LDS traffic, FMA reads A from SGPR.
//   - only W is LDS-staged: [512 n][BK=32 k] panel, 64 KB, 2 blocks/CU.
//   - per wave per k: LDS = 2 b128 B-reads (+~6 write-cyc amortized)
//     -> per-CU demand ~120 cyc per 128 FMA-cyc -> duty ceiling ~95%.
//   - acc is 8x8 = 64 VGPRs; staging regs are R1-style short-lived
//     (load -> one barrier -> write) -> no allocator trap. (256,2) cap 256.
//
// W-panel XOR swizzle (b128-granular): phys_blk = blk ^ rho(n),
// rho(n) = (n>>3)&7.
//   write: thread t stages rows {t, t+256}; rho = (t>>3)&7 (+256 preserves
//     &7) -> lane-octets hit the 8 bank-groups uniformly.
//   read:  lane reads row n = 8*lane+j -> n>>3 = lane -> rho = lane&7 ->
//     8 bank-groups hit uniformly per instruction. Optimal b128 on both
//     sides; SQ_LDS_BANK_CONFLICT expected ~0.
#define BK 32
#define KTILES (I_DIM / BK)

__global__ __launch_bounds__(256, 2) void gemm_bias_f32(
    const float* __restrict__ A,
    const float* __restrict__ Bw,
    const float* __restrict__ bias,
    float* __restrict__ C)
{
    __shared__ float Bs[I_DIM * BK];          // 512 x 32 floats = 64 KB
    float4* Bs4 = (float4*)Bs;                // 4096 b128 blocks

    const int tid  = threadIdx.x;
    const int lane = tid & 63;
    const int w    = tid >> 6;                // wave 0..3
    const int rho_r = lane & 7;               // read swizzle for lane's rows
    const int rho_w = (tid >> 3) & 7;         // write swizzle (rows t, t+256)

    // Wave's m-rows: 8 consecutive rows; block covers 32 rows.
    const float* Aw = A + (size_t)(blockIdx.x * 32 + w * 8) * I_DIM;

    // Staging rows for this thread.
    const int n_a = tid;
    const int n_b = tid + 256;

    float acc[8][8];
    #pragma unroll
    for (int i = 0; i < 8; i++)
        #pragma unroll
        for (int j = 0; j < 8; j++)
            acc[i][j] = 0.0f;

    for (int kt = 0; kt < KTILES; kt++) {
        const int k0 = kt * BK;

        // ---- stage W panel: rows n_a, n_b; 8 float4 each (k0..k0+31) ----
        float4 wva[8], wvb[8];
        #pragma unroll
        for (int b = 0; b < 8; b++)
            wva[b] = *(const float4*)(Bw + (size_t)n_a * I_DIM + k0 + b * 4);
        #pragma unroll
        for (int b = 0; b < 8; b++)
            wvb[b] = *(const float4*)(Bw + (size_t)n_b * I_DIM + k0 + b * 4);

        __syncthreads();   // prior tile's LDS reads complete

        #pragma unroll
        for (int b = 0; b < 8; b++)
            Bs4[n_a * 8 + (b ^ rho_w)] = wva[b];
        #pragma unroll
        for (int b = 0; b < 8; b++)
            Bs4[n_b * 8 + (b ^ rho_w)] = wvb[b];

        __syncthreads();

        // ---- compute: 8 groups of 4 k-steps ----
        #pragma unroll 2
        for (int g = 0; g < 8; g++) {
            // A: wave-uniform float4s (8 rows x 4 k) -> scalar/L1 path
            float4 a4[8];
            #pragma unroll
            for (int i = 0; i < 8; i++)
                a4[i] = *(const float4*)(Aw + (size_t)i * I_DIM + k0 + g * 4);

            // B: lane's 8 n-rows, this k-group (swizzled)
            float4 b4[8];
            #pragma unroll
            for (int j = 0; j < 8; j++)
                b4[j] = Bs4[(lane * 8 + j) * 8 + (g ^ rho_r)];

            // 4 k-steps, ascending k (same accumulation order as reference
            // chain -> absmax 0.0 preserved)
            #pragma unroll
            for (int i = 0; i < 8; i++)
                #pragma unroll
                for (int j = 0; j < 8; j++)
                    acc[i][j] = fmaf(a4[i].x, b4[j].x, acc[i][j]);
            #pragma unroll
            for (int i = 0; i < 8; i++)
                #pragma unroll
                for (int j = 0; j < 8; j++)
                    acc[i][j] = fmaf(a4[i].y, b4[j].y, acc[i][j]);
            #pragma unroll
            for (int i = 0; i < 8; i++)
                #pragma unroll
                for (int j = 0; j < 8; j++)
                    acc[i][j] = fmaf(a4[i].z, b4[j].z, acc[i][j]);
            #pragma unroll
            for (int i = 0; i < 8; i++)
                #pragma unroll
                for (int j = 0; j < 8; j++)
                    acc[i][j] = fmaf(a4[i].w, b4[j].w, acc[i][j]);
        }
    }

    // ---- epilogue: bias + store. Lane's cols: 8*lane .. 8*lane+7 ----
    float4 bi0 = *(const float4*)(bias + lane * 8);
    float4 bi1 = *(const float4*)(bias + lane * 8 + 4);

    const int m0 = blockIdx.x * 32 + w * 8;
    #pragma unroll
    for (int i = 0; i < 8; i++) {
        float4 o0, o1;
        o0.x = acc[i][0] + bi0.x;
        o0.y = acc[i][1] + bi0.y;
        o0.z = acc[i][2] + bi0.z;
        o0.w = acc[i][3] + bi0.w;
        o1.x = acc[i][4] + bi1.x;
        o1.y = acc[i][5] + bi1.y;
        o1.z = acc[i][6] + bi1.z;
        o1.w = acc[i][7] + bi1.w;
        float* cp = C + (size_t)(m0 + i) * H_DIM + lane * 8;
        *(float4*)(cp)     = o0;
        *(float4*)(cp + 4) = o1;
    }
}

// LIF scan over T with warm-up chunking (R6 form, byte-identical;
// correctness proven: absmax 0.0 across three runs).
//
// v <- v/2 + h_t ; s = (v >= 1) ; v <- s ? 0 : v
//
// LIF forgets exponentially: decay 0.5/step -> influence after 32 no-fire
// steps is x2^-32, and any fire resets exactly. 4 chunks of 64 stored steps;
// chunks 1-3 start 32 steps early from v=0 (no stores during warm-up).
// 4096 waves (4/SIMD). NOTE (R6): total-minus-gemm residual is noise-
// dominated (±15-30 us for identical code) — do not churn this kernel.
#define NCHUNK 4
#define TCHUNK (T_STEPS / NCHUNK)   // 64 stored steps per chunk
#define WARM   32                   // warm-up steps (chunks 1..3)
#define SCAN_U 16

__global__ __launch_bounds__(256) void lif_scan(
    const float* __restrict__ h,
    float* __restrict__ out)
{
    const int n     = B_DIM * H_DIM;                    // 65536 neurons
    const int chunk = blockIdx.x & (NCHUNK - 1);
    const int idx   = (blockIdx.x >> 2) * 256 + threadIdx.x;   // neuron id
    const float* hp = h + idx;
    float* op       = out + idx;

    const int t_begin = chunk * TCHUNK;                 // first stored step
    const int t_start = (chunk == 0) ? 0 : t_begin - WARM;
    const int nb      = (t_begin + TCHUNK - t_start) >> 4;   // 4 or 6 batches

    float bufA[SCAN_U], bufB[SCAN_U];
    float sA[SCAN_U], sB[SCAN_U];

    #pragma unroll
    for (int i = 0; i < SCAN_U; i++)
        bufA[i] = hp[(size_t)(t_start + i) * n];

    float v = 0.0f;
    int tb = t_start;
    for (int b = 0; b < nb; b += 2) {
        // prefetch batch b+1 before chewing on batch b
        #pragma unroll
        for (int i = 0; i < SCAN_U; i++)
            bufB[i] = hp[(size_t)(tb + SCAN_U + i) * n];

        #pragma unroll
        for (int i = 0; i < SCAN_U; i++) {
            v = 0.5f * v + bufA[i];
            const bool fire = (v >= 1.0f);
            sA[i] = fire ? 1.0f : 0.0f;
            v     = fire ? 0.0f : v;
        }
        if (tb >= t_begin) {   // wave-uniform: skip stores during warm-up
            #pragma unroll
            for (int i = 0; i < SCAN_U; i++)
                op[(size_t)(tb + i) * n] = sA[i];
        }

        // prefetch batch b+2
        if (b + 2 < nb) {
            #pragma unroll
            for (int i = 0; i < SCAN_U; i++)
                bufA[i] = hp[(size_t)(tb + 2 * SCAN_U + i) * n];
        }

        #pragma unroll
        for (int i = 0; i < SCAN_U; i++) {
            v = 0.5f * v + bufB[i];
            const bool fire = (v >= 1.0f);
            sB[i] = fire ? 1.0f : 0.0f;
            v     = fire ? 0.0f : v;
        }
        if (tb + SCAN_U >= t_begin) {
            #pragma unroll
            for (int i = 0; i < SCAN_U; i++)
                op[(size_t)(tb + SCAN_U + i) * n] = sB[i];
        }

        tb += 2 * SCAN_U;
    }
}

extern "C" void kernel_launch(void* const* d_in, const int* in_sizes, int n_in,
                              void* d_out, int out_size, void* d_ws, size_t ws_size,
                              hipStream_t stream) {
    const float* x = (const float*)d_in[0];   // (T, B, I) fp32
    const float* W = (const float*)d_in[1];   // (H, I)    fp32
    const float* b = (const float*)d_in[2];   // (H,)      fp32
    float* out = (float*)d_out;               // (T, B, H) fp32 spikes
    float* h   = (float*)d_ws;                // (T*B, H) fp32 scratch = 64 MB

    // 32 m-rows per block; each block covers all 512 n-cols.
    gemm_bias_f32<<<M_DIM / 32, 256, 0, stream>>>(x, W, b, h);

    // 4 chunks x (65536/256) neuron-blocks = 1024 blocks, 4096 waves
    lif_scan<<<(B_DIM * H_DIM) / 256 * NCHUNK, 256, 0, stream>>>(h, out);
}

// Round 14
// 300.798 us; speedup vs baseline: 2.1854x; 2.1854x over previous
//
#include <hip/hip_runtime.h>

// Problem dims (from reference setup_inputs): T=256, B=128, I=512, H=512
#define T_STEPS 256
#define B_DIM   128
#define I_DIM   512
#define H_DIM   512

// ================= FUSED GEMM + LIF scan =================
// h[t,b,n] = sum_k x[t,b,k] * W[n,k] + bias[n];  v' = v/2 + h; s = v'>=1;
// v <- s ? 0 : v'.   Spikes written directly; h NEVER goes to HBM.
//
// WHY FUSED: the 8x8/VGPR-60 GEMM core (212 us) is at its LDS-pipe ceiling
// (5 structural attempts to widen the fragment or bypass LDS all collapsed
// under LLVM's occupancy-targeting register allocator: R2/3/5 spill or
// load-sinking, R9 ILP-throttle at VGPR=132, R10 spill + 8-way bank
// conflicts at VGPR=124). The remaining waste was the INTERFACE: 64 MB h
// write + 88 MB h read + a second kernel (~95 us residual). Fusion deletes
// all of it while reusing the proven GEMM core verbatim.
//
// Decomposition: block = (batch-row b, 128-col n-panel); grid (4,128) = 512
// blocks = 2/CU exactly. Outer loop: 2 t-chunks of 128. Per chunk the block
// computes the 128x128x512 tile (m-row r <-> t = t0+r, fixed b), then:
//   acc+bias -> LDS h_tile[128][132] (aliases As/Bs; 67.6 KB; pad +4 keeps
//   float4 alignment and breaks the worst write aliasing), barrier,
//   threads 0..127 scan 128 t-steps (batch-8 ds_reads hide the ~120cyc LDS
//   latency; ~3K cyc per chunk vs ~65K GEMM cyc), store spikes coalesced
//   (512B per t across the half-wave pair).
// v carried in-register across chunks -> EXACT (no warm-up approximation).
// Same fmaf k-order as R4's GEMM + same scan expression -> absmax 0.0.
//
// LDS swizzle (GEMM tiles; SQ_LDS_BANK_CONFLICT==0 verified R1-R9):
// k-major [BK][128], phys_blk = blk ^ rho(k), rho(k)=(k>>2)&7; staging
// rho = tid&7 thread-constant (2-way, free); A-reads broadcast; B-reads 2-way.
//
// (Rounds 11/12 were GPUAcquisitionTimeouts; round 13 a container failure.
// Kernel audited for OOB/hangs — none found; resubmitting identical. If the
// container error repeats, next round submits the R4 known-good to
// disambiguate kernel-triggered vs infra-triggered failure.)
#define BK 32

__global__ __launch_bounds__(256, 2) void fused_gemm_lif(
    const float* __restrict__ A,
    const float* __restrict__ Bw,
    const float* __restrict__ bias,
    float* __restrict__ out)
{
    __shared__ float smem[128 * 132];          // 67.6 KB: h_tile; rows 0..61
    float* Asm = smem;                          //   alias As [32][128] 16 KB
    float* Bsm = smem + BK * 128;               //   alias Bs [32][128] 16 KB

    const int tid = threadIdx.x;
    const int tx  = tid & 15;                  // n dir (16 x 8 floats)
    const int ty  = tid >> 4;                  // m dir (16 x 8 rows)
    const int n0  = blockIdx.x * 128;          // n-panel
    const int b   = blockIdx.y;                // batch row 0..127

    // staging map (proven): thread stages rows lrow+32p, k-cols lk..lk+3
    const int lrow = tid >> 3;
    const int lk   = (tid & 7) * 4;
    const int q    = tid & 7;

    const float* Bptr = Bw + (size_t)(n0 + lrow) * I_DIM + lk;

    const float4 bc0 = *(const float4*)(bias + n0 + tx * 4);
    const float4 bc1 = *(const float4*)(bias + n0 + 64 + tx * 4);

    float v = 0.0f;                            // LIF state (threads 0..127)

    for (int t0 = 0; t0 < T_STEPS; t0 += 128) {
        float acc[8][8];
        #pragma unroll
        for (int i = 0; i < 8; i++)
            #pragma unroll
            for (int j = 0; j < 8; j++)
                acc[i][j] = 0.0f;

        for (int k0 = 0; k0 < I_DIM; k0 += BK) {
            float4 av[4], bv[4];
            #pragma unroll
            for (int p = 0; p < 4; p++) {
                const int t = t0 + lrow + p * 32;       // tile row -> time
                av[p] = *(const float4*)(A + ((size_t)t * B_DIM + b) * I_DIM
                                           + lk + k0);
                bv[p] = *(const float4*)(Bptr + (size_t)(p * 32) * I_DIM + k0);
            }

            __syncthreads();   // prior LDS reads (GEMM or scan) complete

            #pragma unroll
            for (int p = 0; p < 4; p++) {
                const int r    = lrow + p * 32;
                const int base = (((r >> 2) ^ q) << 2) | (r & 3);
                Asm[(lk + 0) * 128 + base] = av[p].x;
                Asm[(lk + 1) * 128 + base] = av[p].y;
                Asm[(lk + 2) * 128 + base] = av[p].z;
                Asm[(lk + 3) * 128 + base] = av[p].w;
                Bsm[(lk + 0) * 128 + base] = bv[p].x;
                Bsm[(lk + 1) * 128 + base] = bv[p].y;
                Bsm[(lk + 2) * 128 + base] = bv[p].z;
                Bsm[(lk + 3) * 128 + base] = bv[p].w;
            }

            __syncthreads();

            const float4* As4 = (const float4*)Asm;
            const float4* Bs4 = (const float4*)Bsm;
            for (int k = 0; k < BK; k++) {
                const int rho = (k >> 2) & 7;
                float4 a0 = As4[k * 32 + ((ty * 2)     ^ rho)];
                float4 a1 = As4[k * 32 + ((ty * 2 + 1) ^ rho)];
                float4 b0 = Bs4[k * 32 + (tx        ^ rho)];
                float4 b1 = Bs4[k * 32 + ((16 + tx) ^ rho)];
                float a[8] = {a0.x, a0.y, a0.z, a0.w, a1.x, a1.y, a1.z, a1.w};
                float bb[8] = {b0.x, b0.y, b0.z, b0.w, b1.x, b1.y, b1.z, b1.w};
                #pragma unroll
                for (int i = 0; i < 8; i++)
                    #pragma unroll
                    for (int j = 0; j < 8; j++)
                        acc[i][j] = fmaf(a[i], bb[j], acc[i][j]);
            }
        }

        __syncthreads();   // all GEMM LDS reads done before h_tile overwrite

        // acc + bias -> h_tile[r][col]; row stride 132 floats (528B: float4-
        // aligned, shifts banks 16B/row to break column aliasing)
        #pragma unroll
        for (int i = 0; i < 8; i++) {
            float* hp = smem + (ty * 8 + i) * 132;
            float4 o0, o1;
            o0.x = acc[i][0] + bc0.x;
            o0.y = acc[i][1] + bc0.y;
            o0.z = acc[i][2] + bc0.z;
            o0.w = acc[i][3] + bc0.w;
            o1.x = acc[i][4] + bc1.x;
            o1.y = acc[i][5] + bc1.y;
            o1.z = acc[i][6] + bc1.z;
            o1.w = acc[i][7] + bc1.w;
            *(float4*)(hp + tx * 4)      = o0;
            *(float4*)(hp + 64 + tx * 4) = o1;
        }

        __syncthreads();

        // LIF scan: thread j (<128) owns neuron (b, n0+j); 128 t-steps.
        // Batch-8 LDS reads pipeline the ~120cyc ds_read latency.
        if (tid < 128) {
            for (int tb = 0; tb < 128; tb += 8) {
                float hv[8];
                #pragma unroll
                for (int i = 0; i < 8; i++)
                    hv[i] = smem[(tb + i) * 132 + tid];
                #pragma unroll
                for (int i = 0; i < 8; i++) {
                    v = 0.5f * v + hv[i];
                    const bool fire = (v >= 1.0f);
                    out[((size_t)(t0 + tb + i) * B_DIM + b) * H_DIM + n0 + tid]
                        = fire ? 1.0f : 0.0f;
                    v = fire ? 0.0f : v;
                }
            }
        }
        // next chunk's first __syncthreads (after its global loads) protects
        // the scan's h_tile reads from the As/Bs overwrite.
    }
}

extern "C" void kernel_launch(void* const* d_in, const int* in_sizes, int n_in,
                              void* d_out, int out_size, void* d_ws, size_t ws_size,
                              hipStream_t stream) {
    const float* x = (const float*)d_in[0];   // (T, B, I) fp32
    const float* W = (const float*)d_in[1];   // (H, I)    fp32
    const float* b = (const float*)d_in[2];   // (H,)      fp32
    float* out = (float*)d_out;               // (T, B, H) fp32 spikes
    (void)d_ws; (void)ws_size;                // h never materialized

    dim3 grid(H_DIM / 128, B_DIM);            // (4, 128) = 512 blocks = 2/CU
    fused_gemm_lif<<<grid, 256, 0, stream>>>(x, W, b, out);
}